// Round 4
// baseline (371.743 us; speedup 1.0000x reference)
//
#include <hip/hip_runtime.h>

// DCP reduction: out = sum_{b,r,c} wy(r)*wx(c)*|min_ch x[b,ch,r,c]|
// x: [16, 3, 1024, 1024] f32.  wy/wx = 2 at borders (r,c in {0,1023}), else 3.
// 3x3 ones-conv (VALID over zero-padded) + global sum == per-pixel window
// coverage-count weighting; pads contribute 0 (channel-min of zeros).
//
// Mapping structure: NTOTAL = 2^19 threads, GROUPS_PER_IMG = 2^18, so each
// thread's within-image offset (and thus h, wcol, all weights) is invariant
// across its 8 iterations; only the image index advances (b = b0 + 2*it,
// address step = 24 MB). Weights applied once after the sum.

#define DCP_HW (1024 * 1024)                     // 2^20
#define GROUPS_PER_IMG (DCP_HW / 4)              // 2^18
#define NGROUPS (16 * GROUPS_PER_IMG)            // 4,194,304

#define NBLOCKS 2048
#define NTHREADS 256
#define NTOTAL (NBLOCKS * NTHREADS)              // 2^19
#define ITERS (NGROUPS / NTOTAL)                 // exactly 8

__global__ __launch_bounds__(NTHREADS) void dcp_kernel(
    const float* __restrict__ x, double* __restrict__ accum,
    unsigned* __restrict__ counter, float* __restrict__ out) {
  const unsigned t = blockIdx.x * NTHREADS + threadIdx.x;  // < 2^19

  // Loop-invariant geometry/weights
  const unsigned rem = (t & (GROUPS_PER_IMG - 1)) << 2;    // pixel offset in image
  const unsigned h = rem >> 10;
  const unsigned wcol = rem & 1023;                        // multiple of 4
  const unsigned b0 = t >> 18;                             // 0 or 1
  const float wx0 = (wcol == 0) ? 2.0f : 3.0f;
  const float wx3 = (wcol == 1020) ? 2.0f : 3.0f;
  const float wy = (h == 0 || h == 1023) ? 2.0f : 3.0f;

  const float* p = x + (size_t)(b0 * 3) * DCP_HW + rem;    // +6*HW floats per iter

  float s0 = 0.0f, smid = 0.0f, s3 = 0.0f;
  #pragma unroll
  for (int it = 0; it < ITERS; ++it) {
    const float* q = p + (size_t)it * (6 * DCP_HW);
    const float4 a0 = *reinterpret_cast<const float4*>(q);
    const float4 a1 = *reinterpret_cast<const float4*>(q + DCP_HW);
    const float4 a2 = *reinterpret_cast<const float4*>(q + 2 * DCP_HW);
    s0   += fabsf(fminf(fminf(a0.x, a1.x), a2.x));
    smid += fabsf(fminf(fminf(a0.y, a1.y), a2.y))
          + fabsf(fminf(fminf(a0.z, a1.z), a2.z));
    s3   += fabsf(fminf(fminf(a0.w, a1.w), a2.w));
  }
  const float accf = wy * (s0 * wx0 + smid * 3.0f + s3 * wx3);

  // Block reduction in double: wave shuffle, then LDS across the 4 waves
  double d = (double)accf;
  #pragma unroll
  for (int off = 32; off > 0; off >>= 1) d += __shfl_down(d, off, 64);

  __shared__ double lds[NTHREADS / 64];
  const int lane = threadIdx.x & 63;
  const int wv = threadIdx.x >> 6;
  if (lane == 0) lds[wv] = d;
  __syncthreads();

  if (threadIdx.x == 0) {
    const double blocksum = lds[0] + lds[1] + lds[2] + lds[3];
    atomicAdd(accum, blocksum);          // device-scope f64 atomic
    __threadfence();                     // release: accum add visible before counter
    const unsigned done = atomicAdd(counter, 1u);
    if (done == NBLOCKS - 1) {
      // All 2048 adds complete & visible (each preceded by a threadfence).
      // Atomic RMW read gets the coherent final value.
      const double total = atomicAdd(accum, 0.0);
      out[0] = (float)total;
    }
  }
}

extern "C" void kernel_launch(void* const* d_in, const int* in_sizes, int n_in,
                              void* d_out, int out_size, void* d_ws, size_t ws_size,
                              hipStream_t stream) {
  const float* x = (const float*)d_in[0];
  // d_in[1] is win_size==3; weight derivation hard-codes K=3.
  float* out = (float*)d_out;
  double* accum = (double*)d_ws;            // 8 B
  unsigned* counter = (unsigned*)((char*)d_ws + 8);  // 4 B

  // d_ws is re-poisoned to 0xAA before every call — zero our 16 bytes.
  hipMemsetAsync(d_ws, 0, 16, stream);
  dcp_kernel<<<NBLOCKS, NTHREADS, 0, stream>>>(x, accum, counter, out);
}

// Round 5
// 274.356 us; speedup vs baseline: 1.3550x; 1.3550x over previous
//
#include <hip/hip_runtime.h>

// DCP reduction: out = sum_{b,r,c} wy(r)*wx(c)*|min_ch x[b,ch,r,c]|
// x: [16, 3, 1024, 1024] f32.  wy/wx = 2 at borders (r,c in {0,1023}), else 3.
// 3x3 ones-conv (VALID over zero-padded) + global sum == per-pixel window
// coverage-count weighting; pads contribute 0 (channel-min of zeros).
//
// R4 post-mortem: single-kernel finalize (2048 same-address f64 atomics +
// __threadfence per block) serialized the tail -> 180 us @ 558 GB/s. Reverted
// to two-kernel partials (R3 structure, no atomics/fences). New lever: loads
// explicitly batched into live register arrays (12 float4 in flight) so the
// compiler can't fall back to a VGPR=32 / 3-loads-at-a-time latency-bound
// schedule.

#define DCP_HW (1024 * 1024)                     // 2^20
#define GROUPS_PER_IMG (DCP_HW / 4)              // 2^18
#define NGROUPS (16 * GROUPS_PER_IMG)            // 4,194,304

#define NBLOCKS 2048
#define NTHREADS 256
#define NTOTAL (NBLOCKS * NTHREADS)              // 2^19
#define ITERS (NGROUPS / NTOTAL)                 // exactly 8

__global__ __launch_bounds__(NTHREADS) void dcp_partial_kernel(
    const float* __restrict__ x, double* __restrict__ part) {
  const unsigned t = blockIdx.x * NTHREADS + threadIdx.x;  // < 2^19

  // Loop-invariant geometry/weights: within-image offset is the same for all
  // 8 iterations (NTOTAL = 2*GROUPS_PER_IMG); only the image index advances.
  const unsigned rem = (t & (GROUPS_PER_IMG - 1)) << 2;    // pixel offset in image
  const unsigned h = rem >> 10;
  const unsigned wcol = rem & 1023;                        // multiple of 4
  const unsigned b0 = t >> 18;                             // 0 or 1
  const float wx0 = (wcol == 0) ? 2.0f : 3.0f;
  const float wx3 = (wcol == 1020) ? 2.0f : 3.0f;
  const float wy = (h == 0 || h == 1023) ? 2.0f : 3.0f;

  const float* p = x + (size_t)(b0 * 3) * DCP_HW + rem;    // +6*HW floats per iter

  float s0 = 0.0f, smid = 0.0f, s3 = 0.0f;

  // Two half-batches: issue 12 global_load_dwordx4 into live registers, THEN
  // reduce. All indices compile-time after unroll (no scratch).
  #pragma unroll
  for (int half = 0; half < 2; ++half) {
    float4 a[4][3];
    #pragma unroll
    for (int i = 0; i < 4; ++i) {
      const float* q = p + (size_t)(half * 4 + i) * (6 * DCP_HW);
      a[i][0] = *reinterpret_cast<const float4*>(q);
      a[i][1] = *reinterpret_cast<const float4*>(q + DCP_HW);
      a[i][2] = *reinterpret_cast<const float4*>(q + 2 * DCP_HW);
    }
    #pragma unroll
    for (int i = 0; i < 4; ++i) {
      s0   += fabsf(fminf(fminf(a[i][0].x, a[i][1].x), a[i][2].x));
      smid += fabsf(fminf(fminf(a[i][0].y, a[i][1].y), a[i][2].y))
            + fabsf(fminf(fminf(a[i][0].z, a[i][1].z), a[i][2].z));
      s3   += fabsf(fminf(fminf(a[i][0].w, a[i][1].w), a[i][2].w));
    }
  }
  const float accf = wy * (s0 * wx0 + smid * 3.0f + s3 * wx3);

  // Block reduction in double: wave shuffle, then LDS across the 4 waves
  double d = (double)accf;
  #pragma unroll
  for (int off = 32; off > 0; off >>= 1) d += __shfl_down(d, off, 64);

  __shared__ double lds[NTHREADS / 64];
  const int lane = threadIdx.x & 63;
  const int wv = threadIdx.x >> 6;
  if (lane == 0) lds[wv] = d;
  __syncthreads();
  if (threadIdx.x == 0) {
    part[blockIdx.x] = lds[0] + lds[1] + lds[2] + lds[3];
  }
}

__global__ __launch_bounds__(256) void dcp_final_kernel(
    const double* __restrict__ part, float* __restrict__ out, int npart) {
  double d = 0.0;
  for (int i = threadIdx.x; i < npart; i += 256) d += part[i];
  #pragma unroll
  for (int off = 32; off > 0; off >>= 1) d += __shfl_down(d, off, 64);

  __shared__ double lds[4];
  const int lane = threadIdx.x & 63;
  const int wv = threadIdx.x >> 6;
  if (lane == 0) lds[wv] = d;
  __syncthreads();
  if (threadIdx.x == 0) out[0] = (float)(lds[0] + lds[1] + lds[2] + lds[3]);
}

extern "C" void kernel_launch(void* const* d_in, const int* in_sizes, int n_in,
                              void* d_out, int out_size, void* d_ws, size_t ws_size,
                              hipStream_t stream) {
  const float* x = (const float*)d_in[0];
  // d_in[1] is win_size==3; weight derivation hard-codes K=3.
  float* out = (float*)d_out;
  double* part = (double*)d_ws;  // NBLOCKS doubles = 16 KB << ws_size; all
                                 // slots written by partial kernel (no memset).

  dcp_partial_kernel<<<NBLOCKS, NTHREADS, 0, stream>>>(x, part);
  dcp_final_kernel<<<1, 256, 0, stream>>>(part, out, NBLOCKS);
}

// Round 8
// 272.734 us; speedup vs baseline: 1.3630x; 1.0059x over previous
//
#include <hip/hip_runtime.h>

// DCP reduction: out = sum_{b,r,c} wy(r)*wx(c)*|min_ch x[b,ch,r,c]|
// x: [16, 3, 1024, 1024] f32.  wy/wx = 2 at borders (r,c in {0,1023}), else 3.
// 3x3 ones-conv (VALID over zero-padded) + global sum == per-pixel window
// coverage weighting; pads contribute 0 (channel-min of zeros).
//
// R5 post-mortem: F (harness resets) ~= 189 us (calibrated from R4's measured
// 180.6 us kernel), so R3/R5 partial kernel ~= 80 us = 2.4 TB/s read — 3x off
// the floor, and 12-deep MLP (R5) == 3-deep (R3) -> not latency-bound.
// Theory: 24 per-thread streams, ALL congruent mod 4 MiB (channel stride 4 MiB
// = L2 size/XCD; image stride 24 MiB) -> L2 set thrash + scattered footprint.
// Fix: one WAVE per image row. Each wave reads 3 plane-rows of 4 KiB
// contiguously; per-thread streams 24 -> 3; j-offsets fit the 13-bit global
// imm (offset:1024*j); weights wave-uniform; 12 loads still fully batched.

#define DCP_HW (1024 * 1024)                 // plane stride, floats
#define NROWS (16 * 1024)                    // 16 images x 1024 rows
#define NBLOCKS (NROWS / 4)                  // 4096: block = 4 rows (4 waves)
#define NTHREADS 256

__global__ __launch_bounds__(NTHREADS) void dcp_partial_kernel(
    const float* __restrict__ x, double* __restrict__ part) {
  const unsigned lane = threadIdx.x & 63;
  const unsigned wv = threadIdx.x >> 6;
  const unsigned R = blockIdx.x * 4 + wv;          // global row id [0, 16384)
  const unsigned b = R >> 10;                      // image
  const unsigned h = R & 1023;                     // row within image

  // Wave covers pixels [h*1024, h*1024+1023] of image b, all 3 channels.
  // Lane i, sub-load j reads float4 at row-offset 256*j + 4*i (floats).
  const float* q0 = x + (size_t)b * (3 * DCP_HW) + (size_t)h * 1024 + 4 * lane;

  // 12 loads batched: 3 channel base addresses, j via 1 KiB immediates.
  float4 a[3][4];
  #pragma unroll
  for (int ch = 0; ch < 3; ++ch) {
    const float* q = q0 + ch * DCP_HW;
    #pragma unroll
    for (int j = 0; j < 4; ++j)
      a[ch][j] = *reinterpret_cast<const float4*>(q + 256 * j);
  }

  // channel-min + abs, per pixel
  float4 m[4];
  #pragma unroll
  for (int j = 0; j < 4; ++j) {
    m[j].x = fabsf(fminf(fminf(a[0][j].x, a[1][j].x), a[2][j].x));
    m[j].y = fabsf(fminf(fminf(a[0][j].y, a[1][j].y), a[2][j].y));
    m[j].z = fabsf(fminf(fminf(a[0][j].z, a[1][j].z), a[2][j].z));
    m[j].w = fabsf(fminf(fminf(a[0][j].w, a[1][j].w), a[2][j].w));
  }

  float s_all = 0.0f;
  #pragma unroll
  for (int j = 0; j < 4; ++j) s_all += (m[j].x + m[j].y) + (m[j].z + m[j].w);

  // weight = wy*wx: wx==3 everywhere except col 0 (lane 0, j0 .x) and
  // col 1023 (lane 63, j3 .w) where wx==2 -> subtract one copy there.
  const float c0 = (lane == 0) ? m[0].x : 0.0f;
  const float c3 = (lane == 63) ? m[3].w : 0.0f;
  const float wy = (h == 0 || h == 1023) ? 2.0f : 3.0f;
  const float accf = wy * (3.0f * s_all - c0 - c3);

  // Block reduction in double: wave shuffle, then LDS across the 4 waves
  double d = (double)accf;
  #pragma unroll
  for (int off = 32; off > 0; off >>= 1) d += __shfl_down(d, off, 64);

  __shared__ double lds[NTHREADS / 64];
  if (lane == 0) lds[wv] = d;
  __syncthreads();
  if (threadIdx.x == 0) {
    part[blockIdx.x] = lds[0] + lds[1] + lds[2] + lds[3];
  }
}

__global__ __launch_bounds__(256) void dcp_final_kernel(
    const double* __restrict__ part, float* __restrict__ out, int npart) {
  double d = 0.0;
  for (int i = threadIdx.x; i < npart; i += 256) d += part[i];
  #pragma unroll
  for (int off = 32; off > 0; off >>= 1) d += __shfl_down(d, off, 64);

  __shared__ double lds[4];
  const int lane = threadIdx.x & 63;
  const int wv = threadIdx.x >> 6;
  if (lane == 0) lds[wv] = d;
  __syncthreads();
  if (threadIdx.x == 0) out[0] = (float)(lds[0] + lds[1] + lds[2] + lds[3]);
}

extern "C" void kernel_launch(void* const* d_in, const int* in_sizes, int n_in,
                              void* d_out, int out_size, void* d_ws, size_t ws_size,
                              hipStream_t stream) {
  const float* x = (const float*)d_in[0];
  // d_in[1] is win_size==3; weight derivation hard-codes K=3.
  float* out = (float*)d_out;
  double* part = (double*)d_ws;  // NBLOCKS doubles = 32 KB << ws_size; every
                                 // slot written by the partial kernel.

  dcp_partial_kernel<<<NBLOCKS, NTHREADS, 0, stream>>>(x, part);
  dcp_final_kernel<<<1, 256, 0, stream>>>(part, out, NBLOCKS);
}